// Round 14
// baseline (1087.291 us; speedup 1.0000x reference)
//
#include <hip/hip_runtime.h>
#include <stdint.h>

// SpatiotemporalAttention: B=16 W=128 S=16 D=768 H=12 HD=64
//  LN1 -> GEMM qkv -> spatial attn (S=16) -> GEMM +resid(f32) -> xs2
//  LN2 -> GEMM tqkv -> temporal attn (W=128, causal, RoPE) -> GEMM +resid -> xt2
//  LN3 -> GEMM f1+gelu -> GEMM f2 +resid -> d_out (f32)
// R14 GEMM: 256x256, BK=64, 8 waves (2x4), per-wave 128x64 output -> 2x the
// FLOP-per-LDS-byte of all prior rounds (R13 diagnosis: LDS-read BW = 88% of
// wall). ONE barrier + one vmcnt(0) per K-tile (R2/R3's 8-barrier lockstep was
// the 256^2 killer). Double-buffered 128KB LDS, compiler counted lgkm waits,
// conflict-free swizzle, T1 XCD y-band.

#define NB 16
#define NW 128
#define NS 16
#define ND 768
#define NH 12
#define NTOK 32768

typedef __attribute__((ext_vector_type(8))) short short8;
typedef __attribute__((ext_vector_type(4))) float f32x4;

__device__ __forceinline__ float blo(unsigned v){ return __builtin_bit_cast(float, v << 16); }
__device__ __forceinline__ float bhi(unsigned v){ return __builtin_bit_cast(float, v & 0xffff0000u); }
__device__ __forceinline__ float bus(unsigned short u){ return __builtin_bit_cast(float, ((unsigned)u) << 16); }
__device__ __forceinline__ unsigned short f2b(float f){
  unsigned u = __builtin_bit_cast(unsigned, f);
  u += 0x7fffu + ((u >> 16) & 1u);
  return (unsigned short)(u >> 16);
}
__device__ __forceinline__ void gld_lds16(const void* g, void* l){
  __builtin_amdgcn_global_load_lds((const __attribute__((address_space(1))) void*)g,
                                   (__attribute__((address_space(3))) void*)l, 16, 0, 0);
}

// ---------------- merged weight convert f32 -> bf16 (8 segments, 1 launch) ----------------
__global__ __launch_bounds__(256) void convertall_k(
    const float* __restrict__ s0, const float* __restrict__ s1, const float* __restrict__ s2,
    const float* __restrict__ s3, const float* __restrict__ s4, const float* __restrict__ s5,
    const float* __restrict__ s6, const float* __restrict__ s7,
    unsigned short* __restrict__ d0, unsigned short* __restrict__ d1, unsigned short* __restrict__ d2,
    unsigned short* __restrict__ d3, unsigned short* __restrict__ d4, unsigned short* __restrict__ d5,
    unsigned short* __restrict__ d6, unsigned short* __restrict__ d7){
  const int n0 = 442368, n1 = 147456, n2 = 147456, n3 = 147456, n4 = 147456, n5 = 147456, n6 = 589824, n7 = 589824;
  const int c0 = n0, c1 = c0+n1, c2 = c1+n2, c3 = c2+n3, c4 = c3+n4, c5 = c4+n5, c6 = c5+n6, c7 = c6+n7;
  int i = blockIdx.x * 256 + threadIdx.x;
  const int stride = gridDim.x * 256;
  for (; i < c7; i += stride){
    const float* s; unsigned short* d; int j;
    if      (i < c0){ s = s0; d = d0; j = i; }
    else if (i < c1){ s = s1; d = d1; j = i - c0; }
    else if (i < c2){ s = s2; d = d2; j = i - c1; }
    else if (i < c3){ s = s3; d = d3; j = i - c2; }
    else if (i < c4){ s = s4; d = d4; j = i - c3; }
    else if (i < c5){ s = s5; d = d5; j = i - c4; }
    else if (i < c6){ s = s6; d = d6; j = i - c5; }
    else            { s = s7; d = d7; j = i - c6; }
    float4 v = ((const float4*)s)[j];
    unsigned lo = (unsigned)f2b(v.x) | ((unsigned)f2b(v.y) << 16);
    unsigned hi = (unsigned)f2b(v.z) | ((unsigned)f2b(v.w) << 16);
    ((uint2*)d)[j] = make_uint2(lo, hi);
  }
}

__global__ __launch_bounds__(256) void concat3_k(const float* __restrict__ a, const float* __restrict__ b,
                                                 const float* __restrict__ c, float* __restrict__ o){
  int i = blockIdx.x * 256 + threadIdx.x;
  if (i < 768){ o[i] = a[i]; o[768 + i] = b[i]; o[1536 + i] = c[i]; }
}

__global__ __launch_bounds__(256) void rope_k(float* __restrict__ tab){
  int i = blockIdx.x * 256 + threadIdx.x;
  if (i < 128 * 32){
    int w = i >> 5, p = i & 31;
    float inv = powf(10000.0f, -((float)(2 * p)) / 64.0f);
    float ang = (float)w * inv;
    tab[i * 2] = cosf(ang);
    tab[i * 2 + 1] = sinf(ang);
  }
}

// ---------------- LayerNorm ----------------
template<int INF32>
__global__ __launch_bounds__(256) void ln_k(const void* __restrict__ xin, const float* __restrict__ g,
                                            const float* __restrict__ bt, unsigned short* __restrict__ out){
  const int row = blockIdx.x;
  const int t = threadIdx.x;
  const float* xf = (const float*)xin;
  const unsigned short* xb = (const unsigned short*)xin;
  float v[3];
#pragma unroll
  for (int i = 0; i < 3; ++i){
    int j = t + i * 256;
    v[i] = INF32 ? xf[(size_t)row * 768 + j] : bus(xb[(size_t)row * 768 + j]);
  }
  float s = v[0] + v[1] + v[2];
  float ss = v[0]*v[0] + v[1]*v[1] + v[2]*v[2];
#pragma unroll
  for (int o = 1; o < 64; o <<= 1){ s += __shfl_xor(s, o, 64); ss += __shfl_xor(ss, o, 64); }
  __shared__ float red[8];
  int w = t >> 6;
  if ((t & 63) == 0){ red[w*2] = s; red[w*2+1] = ss; }
  __syncthreads();
  s = red[0] + red[2] + red[4] + red[6];
  ss = red[1] + red[3] + red[5] + red[7];
  float mean = s * (1.0f / 768.0f);
  float var = ss * (1.0f / 768.0f) - mean * mean;
  float rstd = rsqrtf(var + 1e-5f);
#pragma unroll
  for (int i = 0; i < 3; ++i){
    int j = t + i * 256;
    out[(size_t)row * 768 + j] = f2b((v[i] - mean) * rstd * g[j] + bt[j]);
  }
}

// ---------------- GEMM 256x256 / BK=64 / 8 waves / 1-barrier dbuf ----------------
// out[n][m] = sum_k A[n][k]*Bw[m][k] (+bias, +resid, gelu per MODE)
// MODE 0: bf16=acc+bias  1: bf16=gelu  2: +resid(f32)  3: +resid(bf16)  4: f32 out +resid(bf16)
//
// LDS: A/B each 2 x 32KB buffers (tile = 256 rows x 64 k bf16; 1 row per 128B
// line; chunk kc of row r stored at pos kc^(r&7) -> bank audit: 16 lanes of a
// b128 read = 8 positions x 2 rows = 2-way = free, matches R9/R13 measured 0).
// Staged via linear LDS dest + pre-swizzled per-lane GLOBAL src (rule #21);
// 4 gld_lds per thread per matrix per tile.
// Per-wave output 128x64 (wm=w>>2 in {0,1}: row half; wn=w&3: 64-col slice) ->
// 24 ds_read_b128 per 64 MFMA per tile = 2x intensity of 64x64-wave layouts.
// K-loop per tile t (ONE barrier, one vmcnt):
//  { stage A,B(t+1)->buf[(t+1)&1]; rd b(8); [mh=0: rd a(8); 32 MFMA][mh=1: same];
//    vmcnt(0); barrier }
// No explicit lgkm: compiler emits counted waits (a-reads of mh=1 overlap mh=0
// MFMA in-wave; 8 waves drift inside the barrier window -> LDS and MFMA pipes
// both stay busy). Dbuf proof: reads(t) target buf[t&1], DMA(t+1) the other;
// every wave's vmcnt(0) precedes its barrier => buffer complete before any
// wave's next-tile reads. Tile t's reads drain before its own MFMA (compiler)
// hence before the barrier; buf[t&1] is only overwritten at t+2's stage, one
// full barrier later.
// T1: bijective XCD y-band swizzle (all grids nwg%8==0).
template<int MODE>
__global__ __launch_bounds__(512, 2) void gemm256_k(const unsigned short* __restrict__ A,
                                                    const unsigned short* __restrict__ Bw,
                                                    const float* __restrict__ bias,
                                                    const void* __restrict__ resid,
                                                    void* __restrict__ outp, int K, int M){
  __shared__ char LB[131072];
  char* const Abuf = LB;            // 2 x 32KB
  char* const Bbuf = LB + 65536;    // 2 x 32KB
  const int tid = threadIdx.x;
  const int lane = tid & 63, w = tid >> 6;
  const int llo = lane & 15, lhi = lane >> 4;
  const int wm = w >> 2, wn = w & 3;
  const int NT = K >> 6;

  // T1 swizzle: contiguous y-band per XCD
  const int gx = gridDim.x;
  const int nwg = gx * gridDim.y;
  const int orig = blockIdx.y * gx + blockIdx.x;
  const int lin = (nwg & 7) ? orig : ((orig & 7) * (nwg >> 3) + (orig >> 3));
  const int by = lin / gx, bx = lin - by * gx;
  const int brow = by << 8;
  const int bcol = bx << 8;

  // staging: thread -> rows r0+64j (j=0..3), chunk cp=tid&7; swizzle on global side
  const int r0 = tid >> 3, cp = tid & 7;
  const int swz = (cp << 4) ^ ((r0 & 7) << 4);
  const char* aG = (const char*)(A + (size_t)(brow + r0) * K) + swz;
  const char* bG = (const char*)(Bw + (size_t)(bcol + r0) * K) + swz;
  const int rowJ = K * 128;           // 64 rows (bytes)
  const int ldst = w << 10;           // wave-uniform LDS base (HW adds lane*16)

  auto stage = [&](const char* g, int gb, char* buf){
#pragma unroll
    for (int j = 0; j < 4; ++j)
      gld_lds16(g + gb + j * rowJ, buf + ldst + j * 8192);
  };

  f32x4 acc[8][4];
#pragma unroll
  for (int m = 0; m < 8; ++m)
#pragma unroll
    for (int n = 0; n < 4; ++n) acc[m][n] = f32x4{0.f, 0.f, 0.f, 0.f};

  // prologue: stage tile 0 -> buf0
  stage(aG, 0, Abuf);
  stage(bG, 0, Bbuf);
  asm volatile("s_waitcnt vmcnt(0)" ::: "memory");
  __builtin_amdgcn_s_barrier();

  for (int t = 0; t < NT; ++t){
    if (t + 1 < NT){
      stage(aG, (t + 1) << 7, Abuf + (((t + 1) & 1) << 15));
      stage(bG, (t + 1) << 7, Bbuf + (((t + 1) & 1) << 15));
    }
    const char* Ab = Abuf + ((t & 1) << 15);
    const char* Bb = Bbuf + ((t & 1) << 15);

    short8 b[4][2];
#pragma unroll
    for (int ni = 0; ni < 4; ++ni){
      const int cc = (wn << 6) + (ni << 4) + llo;
#pragma unroll
      for (int ks = 0; ks < 2; ++ks)
        b[ni][ks] = *(const short8*)(Bb + cc * 128 + (((ks << 6) + (lhi << 4)) ^ ((cc & 7) << 4)));
    }
#pragma unroll
    for (int mh = 0; mh < 2; ++mh){
      short8 a[4][2];
#pragma unroll
      for (int mi = 0; mi < 4; ++mi){
        const int rr = (wm << 7) + (mh << 6) + (mi << 4) + llo;
#pragma unroll
        for (int ks = 0; ks < 2; ++ks)
          a[mi][ks] = *(const short8*)(Ab + rr * 128 + (((ks << 6) + (lhi << 4)) ^ ((rr & 7) << 4)));
      }
      __builtin_amdgcn_s_setprio(1);
#pragma unroll
      for (int mi = 0; mi < 4; ++mi)
#pragma unroll
        for (int ni = 0; ni < 4; ++ni){
          acc[mh * 4 + mi][ni] = __builtin_amdgcn_mfma_f32_16x16x32_bf16(b[ni][0], a[mi][0], acc[mh * 4 + mi][ni], 0, 0, 0);
          acc[mh * 4 + mi][ni] = __builtin_amdgcn_mfma_f32_16x16x32_bf16(b[ni][1], a[mi][1], acc[mh * 4 + mi][ni], 0, 0, 0);
        }
      __builtin_amdgcn_s_setprio(0);
    }
    asm volatile("s_waitcnt vmcnt(0)" ::: "memory");
    __builtin_amdgcn_s_barrier();
  }

  // epilogue: lane holds 4 consecutive output COLUMNS per fragment
  const int orow = brow + (wm << 7);
  const int ocol = bcol + (wn << 6);
  const unsigned short* resb = (const unsigned short*)resid;
  const float* resf = (const float*)resid;
#pragma unroll
  for (int m = 0; m < 8; ++m){
    const int row = orow + (m << 4) + llo;
    const size_t rb = (size_t)row * M;
#pragma unroll
    for (int n = 0; n < 4; ++n){
      const int col = ocol + (n << 4) + (lhi << 2);
      const float4 bv = *(const float4*)&bias[col];
      float v0 = acc[m][n][0] + bv.x;
      float v1 = acc[m][n][1] + bv.y;
      float v2 = acc[m][n][2] + bv.z;
      float v3 = acc[m][n][3] + bv.w;
      const size_t off = rb + col;
      if (MODE == 1){
        float y0 = v0 * (1.5957691216f + 0.0713548163f * v0 * v0);
        float y1 = v1 * (1.5957691216f + 0.0713548163f * v1 * v1);
        float y2 = v2 * (1.5957691216f + 0.0713548163f * v2 * v2);
        float y3 = v3 * (1.5957691216f + 0.0713548163f * v3 * v3);
        v0 = v0 / (1.0f + __expf(-y0));
        v1 = v1 / (1.0f + __expf(-y1));
        v2 = v2 / (1.0f + __expf(-y2));
        v3 = v3 / (1.0f + __expf(-y3));
      } else if (MODE == 2){
        const float4 rv = *(const float4*)&resf[off];
        v0 += rv.x; v1 += rv.y; v2 += rv.z; v3 += rv.w;
      } else if (MODE == 3 || MODE == 4){
        const uint2 rv = *(const uint2*)&resb[off];
        v0 += blo(rv.x); v1 += bhi(rv.x); v2 += blo(rv.y); v3 += bhi(rv.y);
      }
      if (MODE == 4){
        float4 ov; ov.x = v0; ov.y = v1; ov.z = v2; ov.w = v3;
        *(float4*)&((float*)outp)[off] = ov;
      } else {
        unsigned lo = (unsigned)f2b(v0) | ((unsigned)f2b(v1) << 16);
        unsigned hi = (unsigned)f2b(v2) | ((unsigned)f2b(v3) << 16);
        *(uint2*)&((unsigned short*)outp)[off] = make_uint2(lo, hi);
      }
    }
  }
}

// ---------------- spatial attention: block = (bw, h), S=16, no mask ----------------
__global__ __launch_bounds__(256) void sattn_k(const unsigned short* __restrict__ qkv,
                                               unsigned short* __restrict__ o){
  const int bw = blockIdx.x, h = blockIdx.y;
  const int t = threadIdx.x;
  __shared__ unsigned short qh[16 * 68], kh[16 * 68], vh[16 * 68];
  __shared__ float pl[16 * 17];
  const int row = t >> 4, c4 = t & 15;
  const size_t base = ((size_t)(bw * 16 + row)) * 2304 + h * 64 + c4 * 4;
  *(uint2*)&qh[row * 68 + c4 * 4] = *(const uint2*)&qkv[base];
  *(uint2*)&kh[row * 68 + c4 * 4] = *(const uint2*)&qkv[base + 768];
  *(uint2*)&vh[row * 68 + c4 * 4] = *(const uint2*)&qkv[base + 1536];
  __syncthreads();

  const int q = row, k = c4;
  float s = 0.f;
#pragma unroll
  for (int c = 0; c < 16; ++c){
    uint2 qv = *(const uint2*)&qh[q * 68 + c * 4];
    uint2 kv = *(const uint2*)&kh[k * 68 + c * 4];
    s += blo(qv.x) * blo(kv.x) + bhi(qv.x) * bhi(kv.x);
    s += blo(qv.y) * blo(kv.y) + bhi(qv.y) * bhi(kv.y);
  }
  s *= 0.125f;
  float m = s;
#pragma unroll
  for (int off = 1; off < 16; off <<= 1) m = fmaxf(m, __shfl_xor(m, off, 64));
  float p = __expf(s - m);
  float su = p;
#pragma unroll
  for (int off = 1; off < 16; off <<= 1) su += __shfl_xor(su, off, 64);
  pl[q * 17 + k] = p / su;
  __syncthreads();

  float o0 = 0.f, o1 = 0.f, o2 = 0.f, o3 = 0.f;
#pragma unroll
  for (int kk = 0; kk < 16; ++kk){
    float pw = pl[q * 17 + kk];
    uint2 vv = *(const uint2*)&vh[kk * 68 + c4 * 4];
    o0 += pw * blo(vv.x); o1 += pw * bhi(vv.x);
    o2 += pw * blo(vv.y); o3 += pw * bhi(vv.y);
  }
  const size_t ob = ((size_t)(bw * 16 + q)) * 768 + h * 64 + c4 * 4;
  unsigned r0 = (unsigned)f2b(o0) | ((unsigned)f2b(o1) << 16);
  unsigned r1 = (unsigned)f2b(o2) | ((unsigned)f2b(o3) << 16);
  *(uint2*)&o[ob] = make_uint2(r0, r1);
}

// ---------------- temporal attention: block = (b*16+s, h), W=128, causal, RoPE ----------------
__global__ __launch_bounds__(256) void tattn_k(const unsigned short* __restrict__ qkv,
                                               const float* __restrict__ rope,
                                               unsigned short* __restrict__ o){
  const int bs = blockIdx.x, h = blockIdx.y;
  const int b = bs >> 4, s = bs & 15;
  const int t = threadIdx.x, lane = t & 63, w = t >> 6;
  const int lhi = lane >> 4, llo = lane & 15;
  __shared__ unsigned short Qs[128 * 64];
  __shared__ unsigned short Ks[128 * 64];
  __shared__ unsigned short Vt[64 * 128];
  __shared__ unsigned short P[128 * 128];

  {
    const int r = t >> 1;
    const int dbase = (t & 1) * 32;
    const size_t tokb = ((size_t)((b * 128 + r) * 16 + s)) * 2304 + h * 64;
    const float2* rp = (const float2*)rope;
#pragma unroll
    for (int mch = 0; mch < 4; ++mch){
      const int d0 = dbase + mch * 8;
      uint4 qv = *(const uint4*)&qkv[tokb + d0];
      uint4 kv = *(const uint4*)&qkv[tokb + 768 + d0];
      uint4 vv = *(const uint4*)&qkv[tokb + 1536 + d0];
      unsigned qin[4] = {qv.x, qv.y, qv.z, qv.w};
      unsigned kin[4] = {kv.x, kv.y, kv.z, kv.w};
      unsigned qo[4], ko[4];
#pragma unroll
      for (int j = 0; j < 4; ++j){
        float2 cssn = rp[r * 32 + (d0 >> 1) + j];
        float cs = cssn.x, sn = cssn.y;
        float qe = blo(qin[j]), qd = bhi(qin[j]);
        float ke = blo(kin[j]), kd = bhi(kin[j]);
        qo[j] = (unsigned)f2b(qe * cs - qd * sn) | ((unsigned)f2b(qe * sn + qd * cs) << 16);
        ko[j] = (unsigned)f2b(ke * cs - kd * sn) | ((unsigned)f2b(ke * sn + kd * cs) << 16);
      }
      const int byq = r * 128 + ((d0 * 2) ^ ((r & 7) << 4));
      *(uint4*)((char*)Qs + byq) = make_uint4(qo[0], qo[1], qo[2], qo[3]);
      *(uint4*)((char*)Ks + byq) = make_uint4(ko[0], ko[1], ko[2], ko[3]);
      unsigned vin[4] = {vv.x, vv.y, vv.z, vv.w};
#pragma unroll
      for (int j = 0; j < 8; ++j){
        const int d = d0 + j;
        unsigned short val = (j & 1) ? (unsigned short)(vin[j >> 1] >> 16)
                                     : (unsigned short)(vin[j >> 1] & 0xffffu);
        *(unsigned short*)((char*)Vt + d * 256 + ((r * 2) ^ ((d & 7) << 4))) = val;
      }
    }
  }
  __syncthreads();

  const int qbase = w * 32;
  f32x4 st[8][2];
#pragma unroll
  for (int i = 0; i < 8; ++i){ st[i][0] = f32x4{0.f,0.f,0.f,0.f}; st[i][1] = f32x4{0.f,0.f,0.f,0.f}; }
#pragma unroll
  for (int kd = 0; kd < 2; ++kd){
    short8 bq[2];
#pragma unroll
    for (int fq = 0; fq < 2; ++fq){
      const int qr = qbase + fq * 16 + llo;
      bq[fq] = *(const short8*)((const char*)Qs + qr * 128 + ((kd * 64 + lhi * 16) ^ ((qr & 7) << 4)));
    }
#pragma unroll
    for (int fk = 0; fk < 8; ++fk){
      const int kr = fk * 16 + llo;
      short8 ak = *(const short8*)((const char*)Ks + kr * 128 + ((kd * 64 + lhi * 16) ^ ((kr & 7) << 4)));
      st[fk][0] = __builtin_amdgcn_mfma_f32_16x16x32_bf16(ak, bq[0], st[fk][0], 0, 0, 0);
      st[fk][1] = __builtin_amdgcn_mfma_f32_16x16x32_bf16(ak, bq[1], st[fk][1], 0, 0, 0);
    }
  }

#pragma unroll
  for (int fq = 0; fq < 2; ++fq){
    const int qg = qbase + fq * 16 + llo;
    float m = -1e30f;
#pragma unroll
    for (int fk = 0; fk < 8; ++fk)
#pragma unroll
      for (int rr = 0; rr < 4; ++rr){
        const int kg = fk * 16 + lhi * 4 + rr;
        float sv = (kg <= qg) ? st[fk][fq][rr] : -1e30f;
        st[fk][fq][rr] = sv;
        m = fmaxf(m, sv);
      }
    m = fmaxf(m, __shfl_xor(m, 16, 64));
    m = fmaxf(m, __shfl_xor(m, 32, 64));
    float su = 0.f;
#pragma unroll
    for (int fk = 0; fk < 8; ++fk)
#pragma unroll
      for (int rr = 0; rr < 4; ++rr){
        float p = __expf((st[fk][fq][rr] - m) * 0.125f);
        st[fk][fq][rr] = p;
        su += p;
      }
    su += __shfl_xor(su, 16, 64);
    su += __shfl_xor(su, 32, 64);
    const float rs = 1.0f / su;
#pragma unroll
    for (int fk = 0; fk < 8; ++fk){
      const int kk = fk * 16 + lhi * 4;
      unsigned lo = (unsigned)f2b(st[fk][fq][0] * rs) | ((unsigned)f2b(st[fk][fq][1] * rs) << 16);
      unsigned hi = (unsigned)f2b(st[fk][fq][2] * rs) | ((unsigned)f2b(st[fk][fq][3] * rs) << 16);
      *(uint2*)((char*)P + qg * 256 + ((kk * 2) ^ ((qg & 7) << 4))) = make_uint2(lo, hi);
    }
  }
  __syncthreads();

  f32x4 oacc[2][4];
#pragma unroll
  for (int i = 0; i < 2; ++i)
#pragma unroll
    for (int j = 0; j < 4; ++j) oacc[i][j] = f32x4{0.f,0.f,0.f,0.f};
#pragma unroll
  for (int ks = 0; ks < 4; ++ks){
    short8 pa[2];
#pragma unroll
    for (int fq = 0; fq < 2; ++fq){
      const int qr = qbase + fq * 16 + llo;
      pa[fq] = *(const short8*)((const char*)P + qr * 256 + ((ks * 64 + lhi * 16) ^ ((qr & 7) << 4)));
    }
#pragma unroll
    for (int fd = 0; fd < 4; ++fd){
      const int dr = fd * 16 + llo;
      short8 vb = *(const short8*)((const char*)Vt + dr * 256 + ((ks * 64 + lhi * 16) ^ ((dr & 7) << 4)));
      oacc[0][fd] = __builtin_amdgcn_mfma_f32_16x16x32_bf16(pa[0], vb, oacc[0][fd], 0, 0, 0);
      oacc[1][fd] = __builtin_amdgcn_mfma_f32_16x16x32_bf16(pa[1], vb, oacc[1][fd], 0, 0, 0);
    }
  }

#pragma unroll
  for (int fq = 0; fq < 2; ++fq)
#pragma unroll
    for (int fd = 0; fd < 4; ++fd)
#pragma unroll
      for (int rr = 0; rr < 4; ++rr){
        const int qg = qbase + fq * 16 + lhi * 4 + rr;
        const int d = fd * 16 + llo;
        const size_t ob = ((size_t)((b * 128 + qg) * 16 + s)) * 768 + h * 64 + d;
        o[ob] = f2b(oacc[fq][fd][rr]);
      }
}

__global__ __launch_bounds__(256) void sentinel_k(float* out){
  if (blockIdx.x == 0 && threadIdx.x == 0) out[0] = 12345.0f;
}

// ---------------- launch ----------------
extern "C" void kernel_launch(void* const* d_in, const int* in_sizes, int n_in,
                              void* d_out, int out_size, void* d_ws, size_t ws_size,
                              hipStream_t stream){
  const float* x       = (const float*)d_in[0];
  const float* sn_g    = (const float*)d_in[2];
  const float* sn_b    = (const float*)d_in[3];
  const float* sa_in_w = (const float*)d_in[4];
  const float* sa_in_b = (const float*)d_in[5];
  const float* sa_out_w= (const float*)d_in[6];
  const float* sa_out_b= (const float*)d_in[7];
  const float* tn_g    = (const float*)d_in[8];
  const float* tn_b    = (const float*)d_in[9];
  const float* tq_w    = (const float*)d_in[10];
  const float* tq_b    = (const float*)d_in[11];
  const float* tk_w    = (const float*)d_in[12];
  const float* tk_b    = (const float*)d_in[13];
  const float* tv_w    = (const float*)d_in[14];
  const float* tv_b    = (const float*)d_in[15];
  const float* to_w    = (const float*)d_in[16];
  const float* to_b    = (const float*)d_in[17];
  const float* fn_g    = (const float*)d_in[18];
  const float* fn_b    = (const float*)d_in[19];
  const float* f1_w    = (const float*)d_in[20];
  const float* f1_b    = (const float*)d_in[21];
  const float* f2_w    = (const float*)d_in[22];
  const float* f2_b    = (const float*)d_in[23];

  char* ws = (char*)d_ws;
  size_t off = 0;
  auto alloc = [&](size_t bytes) -> void* {
    void* p = ws + off;
    off += (bytes + 255) & ~(size_t)255;
    return p;
  };
  unsigned short* Wqkv = (unsigned short*)alloc((size_t)2304*768*2);
  unsigned short* Wo1  = (unsigned short*)alloc((size_t)768*768*2);
  unsigned short* W3   = (unsigned short*)alloc((size_t)2304*768*2);
  float*          b3   = (float*)alloc(2304*4);
  unsigned short* Wto  = (unsigned short*)alloc((size_t)768*768*2);
  unsigned short* Wf1  = (unsigned short*)alloc((size_t)3072*768*2);
  unsigned short* Wf2  = (unsigned short*)alloc((size_t)768*3072*2);
  float*          rope = (float*)alloc(128*32*2*4);
  unsigned short* xn   = (unsigned short*)alloc((size_t)NTOK*768*2);
  unsigned short* qkv  = (unsigned short*)alloc((size_t)NTOK*3072*2);
  unsigned short* xs2  = (unsigned short*)alloc((size_t)NTOK*768*2);
  unsigned short* xt2  = (unsigned short*)alloc((size_t)NTOK*768*2);
  unsigned short* ob   = xn; // alias: xn dead when attn output written

  if (ws_size < off){ sentinel_k<<<1, 64, 0, stream>>>((float*)d_out); return; }

  convertall_k<<<2048, 256, 0, stream>>>(sa_in_w, sa_out_w, tq_w, tk_w, tv_w, to_w, f1_w, f2_w,
                                         Wqkv, Wo1, W3, W3 + 768*768, W3 + 2*768*768, Wto, Wf1, Wf2);
  concat3_k<<<3, 256, 0, stream>>>(tq_b, tk_b, tv_b, b3);
  rope_k<<<16, 256, 0, stream>>>(rope);

  // spatial block
  ln_k<1><<<NTOK, 256, 0, stream>>>(x, sn_g, sn_b, xn);
  gemm256_k<0><<<dim3(9, 128), 512, 0, stream>>>(xn, Wqkv, sa_in_b, nullptr, qkv, 768, 2304);
  sattn_k<<<dim3(2048, 12), 256, 0, stream>>>(qkv, ob);
  gemm256_k<2><<<dim3(3, 128), 512, 0, stream>>>(ob, Wo1, sa_out_b, x, xs2, 768, 768);

  // temporal block
  ln_k<0><<<NTOK, 256, 0, stream>>>(xs2, tn_g, tn_b, xn);
  gemm256_k<0><<<dim3(9, 128), 512, 0, stream>>>(xn, W3, b3, nullptr, qkv, 768, 2304);
  tattn_k<<<dim3(256, 12), 256, 0, stream>>>(qkv, rope, ob);
  gemm256_k<3><<<dim3(3, 128), 512, 0, stream>>>(ob, Wto, to_b, xs2, xt2, 768, 768);

  // FFN
  ln_k<0><<<NTOK, 256, 0, stream>>>(xt2, fn_g, fn_b, xn);
  gemm256_k<1><<<dim3(12, 128), 512, 0, stream>>>(xn, Wf1, f1_b, nullptr, qkv, 768, 3072);
  gemm256_k<4><<<dim3(3, 128), 512, 0, stream>>>(qkv, Wf2, f2_b, xt2, d_out, 3072, 768);
}

// Round 15
// 1081.561 us; speedup vs baseline: 1.0053x; 1.0053x over previous
//
#include <hip/hip_runtime.h>
#include <stdint.h>

// SpatiotemporalAttention: B=16 W=128 S=16 D=768 H=12 HD=64
//  LN1 -> GEMM qkv -> spatial attn (S=16) -> GEMM +resid(f32) -> xs2
//  LN2 -> GEMM tqkv -> temporal attn (W=128, causal, RoPE) -> GEMM +resid -> xt2
//  LN3 -> GEMM f1+gelu -> GEMM f2 +resid -> d_out (f32)
// R15 = R14 + in-tile reordering: all 24 ds_reads issued upfront in consumption
// order; MFMA ks-outer (4 clusters of 16 independent MFMAs; dependent pairs 16
// apart; first cluster gated on 8 reads not 16). Sync/dbuf/swizzle unchanged.

#define NB 16
#define NW 128
#define NS 16
#define ND 768
#define NH 12
#define NTOK 32768

typedef __attribute__((ext_vector_type(8))) short short8;
typedef __attribute__((ext_vector_type(4))) float f32x4;

__device__ __forceinline__ float blo(unsigned v){ return __builtin_bit_cast(float, v << 16); }
__device__ __forceinline__ float bhi(unsigned v){ return __builtin_bit_cast(float, v & 0xffff0000u); }
__device__ __forceinline__ float bus(unsigned short u){ return __builtin_bit_cast(float, ((unsigned)u) << 16); }
__device__ __forceinline__ unsigned short f2b(float f){
  unsigned u = __builtin_bit_cast(unsigned, f);
  u += 0x7fffu + ((u >> 16) & 1u);
  return (unsigned short)(u >> 16);
}
__device__ __forceinline__ void gld_lds16(const void* g, void* l){
  __builtin_amdgcn_global_load_lds((const __attribute__((address_space(1))) void*)g,
                                   (__attribute__((address_space(3))) void*)l, 16, 0, 0);
}

// ---------------- merged weight convert f32 -> bf16 (8 segments, 1 launch) ----------------
__global__ __launch_bounds__(256) void convertall_k(
    const float* __restrict__ s0, const float* __restrict__ s1, const float* __restrict__ s2,
    const float* __restrict__ s3, const float* __restrict__ s4, const float* __restrict__ s5,
    const float* __restrict__ s6, const float* __restrict__ s7,
    unsigned short* __restrict__ d0, unsigned short* __restrict__ d1, unsigned short* __restrict__ d2,
    unsigned short* __restrict__ d3, unsigned short* __restrict__ d4, unsigned short* __restrict__ d5,
    unsigned short* __restrict__ d6, unsigned short* __restrict__ d7){
  const int n0 = 442368, n1 = 147456, n2 = 147456, n3 = 147456, n4 = 147456, n5 = 147456, n6 = 589824, n7 = 589824;
  const int c0 = n0, c1 = c0+n1, c2 = c1+n2, c3 = c2+n3, c4 = c3+n4, c5 = c4+n5, c6 = c5+n6, c7 = c6+n7;
  int i = blockIdx.x * 256 + threadIdx.x;
  const int stride = gridDim.x * 256;
  for (; i < c7; i += stride){
    const float* s; unsigned short* d; int j;
    if      (i < c0){ s = s0; d = d0; j = i; }
    else if (i < c1){ s = s1; d = d1; j = i - c0; }
    else if (i < c2){ s = s2; d = d2; j = i - c1; }
    else if (i < c3){ s = s3; d = d3; j = i - c2; }
    else if (i < c4){ s = s4; d = d4; j = i - c3; }
    else if (i < c5){ s = s5; d = d5; j = i - c4; }
    else if (i < c6){ s = s6; d = d6; j = i - c5; }
    else            { s = s7; d = d7; j = i - c6; }
    float4 v = ((const float4*)s)[j];
    unsigned lo = (unsigned)f2b(v.x) | ((unsigned)f2b(v.y) << 16);
    unsigned hi = (unsigned)f2b(v.z) | ((unsigned)f2b(v.w) << 16);
    ((uint2*)d)[j] = make_uint2(lo, hi);
  }
}

__global__ __launch_bounds__(256) void concat3_k(const float* __restrict__ a, const float* __restrict__ b,
                                                 const float* __restrict__ c, float* __restrict__ o){
  int i = blockIdx.x * 256 + threadIdx.x;
  if (i < 768){ o[i] = a[i]; o[768 + i] = b[i]; o[1536 + i] = c[i]; }
}

__global__ __launch_bounds__(256) void rope_k(float* __restrict__ tab){
  int i = blockIdx.x * 256 + threadIdx.x;
  if (i < 128 * 32){
    int w = i >> 5, p = i & 31;
    float inv = powf(10000.0f, -((float)(2 * p)) / 64.0f);
    float ang = (float)w * inv;
    tab[i * 2] = cosf(ang);
    tab[i * 2 + 1] = sinf(ang);
  }
}

// ---------------- LayerNorm ----------------
template<int INF32>
__global__ __launch_bounds__(256) void ln_k(const void* __restrict__ xin, const float* __restrict__ g,
                                            const float* __restrict__ bt, unsigned short* __restrict__ out){
  const int row = blockIdx.x;
  const int t = threadIdx.x;
  const float* xf = (const float*)xin;
  const unsigned short* xb = (const unsigned short*)xin;
  float v[3];
#pragma unroll
  for (int i = 0; i < 3; ++i){
    int j = t + i * 256;
    v[i] = INF32 ? xf[(size_t)row * 768 + j] : bus(xb[(size_t)row * 768 + j]);
  }
  float s = v[0] + v[1] + v[2];
  float ss = v[0]*v[0] + v[1]*v[1] + v[2]*v[2];
#pragma unroll
  for (int o = 1; o < 64; o <<= 1){ s += __shfl_xor(s, o, 64); ss += __shfl_xor(ss, o, 64); }
  __shared__ float red[8];
  int w = t >> 6;
  if ((t & 63) == 0){ red[w*2] = s; red[w*2+1] = ss; }
  __syncthreads();
  s = red[0] + red[2] + red[4] + red[6];
  ss = red[1] + red[3] + red[5] + red[7];
  float mean = s * (1.0f / 768.0f);
  float var = ss * (1.0f / 768.0f) - mean * mean;
  float rstd = rsqrtf(var + 1e-5f);
#pragma unroll
  for (int i = 0; i < 3; ++i){
    int j = t + i * 256;
    out[(size_t)row * 768 + j] = f2b((v[i] - mean) * rstd * g[j] + bt[j]);
  }
}

// ---------------- GEMM 256x256 / BK=64 / 8 waves / 1-barrier dbuf ----------------
// out[n][m] = sum_k A[n][k]*Bw[m][k] (+bias, +resid, gelu per MODE)
// MODE 0: bf16=acc+bias  1: bf16=gelu  2: +resid(f32)  3: +resid(bf16)  4: f32 out +resid(bf16)
//
// LDS: A/B each 2x32KB buffers (256 rows x 64 k; 1 row per 128B line; chunk kc
// at pos kc^(r&7) -> 2-way bank access = free, measured 0). Linear LDS dest +
// pre-swizzled global src (rule #21). Per-wave output 128x64.
// K-loop per tile t (ONE barrier, one vmcnt):
//  { stage A,B(t+1)->other buf; issue ALL 24 ds_reads in consumption order
//    (b ks0, a-mh0 ks0, b ks1, a-mh0 ks1, a-mh1 ks0, a-mh1 ks1);
//    4 MFMA clusters of 16 independent (ks-outer; dependent acc-pairs 16 apart;
//    cluster 1 gated on only 8 reads via compiler counted lgkm);
//    vmcnt(0); barrier }
// Dbuf proof (R14): reads(t) -> buf[t&1], DMA(t+1) -> other; every wave's
// vmcnt(0) precedes its barrier => buffer complete before any next-tile read;
// buf[t&1] overwritten only at t+2's stage, one barrier later.
// T1: bijective XCD y-band swizzle (all grids nwg%8==0).
template<int MODE>
__global__ __launch_bounds__(512, 2) void gemm256_k(const unsigned short* __restrict__ A,
                                                    const unsigned short* __restrict__ Bw,
                                                    const float* __restrict__ bias,
                                                    const void* __restrict__ resid,
                                                    void* __restrict__ outp, int K, int M){
  __shared__ char LB[131072];
  char* const Abuf = LB;            // 2 x 32KB
  char* const Bbuf = LB + 65536;    // 2 x 32KB
  const int tid = threadIdx.x;
  const int lane = tid & 63, w = tid >> 6;
  const int llo = lane & 15, lhi = lane >> 4;
  const int wm = w >> 2, wn = w & 3;
  const int NT = K >> 6;

  // T1 swizzle: contiguous y-band per XCD
  const int gx = gridDim.x;
  const int nwg = gx * gridDim.y;
  const int orig = blockIdx.y * gx + blockIdx.x;
  const int lin = (nwg & 7) ? orig : ((orig & 7) * (nwg >> 3) + (orig >> 3));
  const int by = lin / gx, bx = lin - by * gx;
  const int brow = by << 8;
  const int bcol = bx << 8;

  // staging: thread -> rows r0+64j (j=0..3), chunk cp=tid&7; swizzle on global side
  const int r0 = tid >> 3, cp = tid & 7;
  const int swz = (cp << 4) ^ ((r0 & 7) << 4);
  const char* aG = (const char*)(A + (size_t)(brow + r0) * K) + swz;
  const char* bG = (const char*)(Bw + (size_t)(bcol + r0) * K) + swz;
  const int rowJ = K * 128;           // 64 rows (bytes)
  const int ldst = w << 10;           // wave-uniform LDS base (HW adds lane*16)

  auto stage = [&](const char* g, int gb, char* buf){
#pragma unroll
    for (int j = 0; j < 4; ++j)
      gld_lds16(g + gb + j * rowJ, buf + ldst + j * 8192);
  };

  f32x4 acc[8][4];
#pragma unroll
  for (int m = 0; m < 8; ++m)
#pragma unroll
    for (int n = 0; n < 4; ++n) acc[m][n] = f32x4{0.f, 0.f, 0.f, 0.f};

  // read helpers (byte offsets computed per tile; compiler hoists invariants)
  auto rd_b4 = [&](short8 (&dst)[4], const char* Bb, int ks){
#pragma unroll
    for (int ni = 0; ni < 4; ++ni){
      const int cc = (wn << 6) + (ni << 4) + llo;
      dst[ni] = *(const short8*)(Bb + cc * 128 + (((ks << 6) + (lhi << 4)) ^ ((cc & 7) << 4)));
    }
  };
  auto rd_a4 = [&](short8 (&dst)[4], const char* Ab, int mh, int ks){
#pragma unroll
    for (int mi = 0; mi < 4; ++mi){
      const int rr = (wm << 7) + (mh << 6) + (mi << 4) + llo;
      dst[mi] = *(const short8*)(Ab + rr * 128 + (((ks << 6) + (lhi << 4)) ^ ((rr & 7) << 4)));
    }
  };

  // prologue: stage tile 0 -> buf0
  stage(aG, 0, Abuf);
  stage(bG, 0, Bbuf);
  asm volatile("s_waitcnt vmcnt(0)" ::: "memory");
  __builtin_amdgcn_s_barrier();

  for (int t = 0; t < NT; ++t){
    if (t + 1 < NT){
      stage(aG, (t + 1) << 7, Abuf + (((t + 1) & 1) << 15));
      stage(bG, (t + 1) << 7, Bbuf + (((t + 1) & 1) << 15));
    }
    const char* Ab = Abuf + ((t & 1) << 15);
    const char* Bb = Bbuf + ((t & 1) << 15);

    // all 24 reads, consumption order
    short8 b0[4], b1[4], a00[4], a01[4], a10[4], a11[4];
    rd_b4(b0, Bb, 0);
    rd_a4(a00, Ab, 0, 0);
    rd_b4(b1, Bb, 1);
    rd_a4(a01, Ab, 0, 1);
    rd_a4(a10, Ab, 1, 0);
    rd_a4(a11, Ab, 1, 1);

    // 4 clusters of 16 independent MFMAs (ks-outer)
    __builtin_amdgcn_s_setprio(1);
#pragma unroll
    for (int mi = 0; mi < 4; ++mi)
#pragma unroll
      for (int ni = 0; ni < 4; ++ni)
        acc[mi][ni] = __builtin_amdgcn_mfma_f32_16x16x32_bf16(b0[ni], a00[mi], acc[mi][ni], 0, 0, 0);
#pragma unroll
    for (int mi = 0; mi < 4; ++mi)
#pragma unroll
      for (int ni = 0; ni < 4; ++ni)
        acc[mi][ni] = __builtin_amdgcn_mfma_f32_16x16x32_bf16(b1[ni], a01[mi], acc[mi][ni], 0, 0, 0);
#pragma unroll
    for (int mi = 0; mi < 4; ++mi)
#pragma unroll
      for (int ni = 0; ni < 4; ++ni)
        acc[4 + mi][ni] = __builtin_amdgcn_mfma_f32_16x16x32_bf16(b0[ni], a10[mi], acc[4 + mi][ni], 0, 0, 0);
#pragma unroll
    for (int mi = 0; mi < 4; ++mi)
#pragma unroll
      for (int ni = 0; ni < 4; ++ni)
        acc[4 + mi][ni] = __builtin_amdgcn_mfma_f32_16x16x32_bf16(b1[ni], a11[mi], acc[4 + mi][ni], 0, 0, 0);
    __builtin_amdgcn_s_setprio(0);

    asm volatile("s_waitcnt vmcnt(0)" ::: "memory");
    __builtin_amdgcn_s_barrier();
  }

  // epilogue: lane holds 4 consecutive output COLUMNS per fragment
  const int orow = brow + (wm << 7);
  const int ocol = bcol + (wn << 6);
  const unsigned short* resb = (const unsigned short*)resid;
  const float* resf = (const float*)resid;
#pragma unroll
  for (int m = 0; m < 8; ++m){
    const int row = orow + (m << 4) + llo;
    const size_t rb = (size_t)row * M;
#pragma unroll
    for (int n = 0; n < 4; ++n){
      const int col = ocol + (n << 4) + (lhi << 2);
      const float4 bv = *(const float4*)&bias[col];
      float v0 = acc[m][n][0] + bv.x;
      float v1 = acc[m][n][1] + bv.y;
      float v2 = acc[m][n][2] + bv.z;
      float v3 = acc[m][n][3] + bv.w;
      const size_t off = rb + col;
      if (MODE == 1){
        float y0 = v0 * (1.5957691216f + 0.0713548163f * v0 * v0);
        float y1 = v1 * (1.5957691216f + 0.0713548163f * v1 * v1);
        float y2 = v2 * (1.5957691216f + 0.0713548163f * v2 * v2);
        float y3 = v3 * (1.5957691216f + 0.0713548163f * v3 * v3);
        v0 = v0 / (1.0f + __expf(-y0));
        v1 = v1 / (1.0f + __expf(-y1));
        v2 = v2 / (1.0f + __expf(-y2));
        v3 = v3 / (1.0f + __expf(-y3));
      } else if (MODE == 2){
        const float4 rv = *(const float4*)&resf[off];
        v0 += rv.x; v1 += rv.y; v2 += rv.z; v3 += rv.w;
      } else if (MODE == 3 || MODE == 4){
        const uint2 rv = *(const uint2*)&resb[off];
        v0 += blo(rv.x); v1 += bhi(rv.x); v2 += blo(rv.y); v3 += bhi(rv.y);
      }
      if (MODE == 4){
        float4 ov; ov.x = v0; ov.y = v1; ov.z = v2; ov.w = v3;
        *(float4*)&((float*)outp)[off] = ov;
      } else {
        unsigned lo = (unsigned)f2b(v0) | ((unsigned)f2b(v1) << 16);
        unsigned hi = (unsigned)f2b(v2) | ((unsigned)f2b(v3) << 16);
        *(uint2*)&((unsigned short*)outp)[off] = make_uint2(lo, hi);
      }
    }
  }
}

// ---------------- spatial attention: block = (bw, h), S=16, no mask ----------------
__global__ __launch_bounds__(256) void sattn_k(const unsigned short* __restrict__ qkv,
                                               unsigned short* __restrict__ o){
  const int bw = blockIdx.x, h = blockIdx.y;
  const int t = threadIdx.x;
  __shared__ unsigned short qh[16 * 68], kh[16 * 68], vh[16 * 68];
  __shared__ float pl[16 * 17];
  const int row = t >> 4, c4 = t & 15;
  const size_t base = ((size_t)(bw * 16 + row)) * 2304 + h * 64 + c4 * 4;
  *(uint2*)&qh[row * 68 + c4 * 4] = *(const uint2*)&qkv[base];
  *(uint2*)&kh[row * 68 + c4 * 4] = *(const uint2*)&qkv[base + 768];
  *(uint2*)&vh[row * 68 + c4 * 4] = *(const uint2*)&qkv[base + 1536];
  __syncthreads();

  const int q = row, k = c4;
  float s = 0.f;
#pragma unroll
  for (int c = 0; c < 16; ++c){
    uint2 qv = *(const uint2*)&qh[q * 68 + c * 4];
    uint2 kv = *(const uint2*)&kh[k * 68 + c * 4];
    s += blo(qv.x) * blo(kv.x) + bhi(qv.x) * bhi(kv.x);
    s += blo(qv.y) * blo(kv.y) + bhi(qv.y) * bhi(kv.y);
  }
  s *= 0.125f;
  float m = s;
#pragma unroll
  for (int off = 1; off < 16; off <<= 1) m = fmaxf(m, __shfl_xor(m, off, 64));
  float p = __expf(s - m);
  float su = p;
#pragma unroll
  for (int off = 1; off < 16; off <<= 1) su += __shfl_xor(su, off, 64);
  pl[q * 17 + k] = p / su;
  __syncthreads();

  float o0 = 0.f, o1 = 0.f, o2 = 0.f, o3 = 0.f;
#pragma unroll
  for (int kk = 0; kk < 16; ++kk){
    float pw = pl[q * 17 + kk];
    uint2 vv = *(const uint2*)&vh[kk * 68 + c4 * 4];
    o0 += pw * blo(vv.x); o1 += pw * bhi(vv.x);
    o2 += pw * blo(vv.y); o3 += pw * bhi(vv.y);
  }
  const size_t ob = ((size_t)(bw * 16 + q)) * 768 + h * 64 + c4 * 4;
  unsigned r0 = (unsigned)f2b(o0) | ((unsigned)f2b(o1) << 16);
  unsigned r1 = (unsigned)f2b(o2) | ((unsigned)f2b(o3) << 16);
  *(uint2*)&o[ob] = make_uint2(r0, r1);
}

// ---------------- temporal attention: block = (b*16+s, h), W=128, causal, RoPE ----------------
__global__ __launch_bounds__(256) void tattn_k(const unsigned short* __restrict__ qkv,
                                               const float* __restrict__ rope,
                                               unsigned short* __restrict__ o){
  const int bs = blockIdx.x, h = blockIdx.y;
  const int b = bs >> 4, s = bs & 15;
  const int t = threadIdx.x, lane = t & 63, w = t >> 6;
  const int lhi = lane >> 4, llo = lane & 15;
  __shared__ unsigned short Qs[128 * 64];
  __shared__ unsigned short Ks[128 * 64];
  __shared__ unsigned short Vt[64 * 128];
  __shared__ unsigned short P[128 * 128];

  {
    const int r = t >> 1;
    const int dbase = (t & 1) * 32;
    const size_t tokb = ((size_t)((b * 128 + r) * 16 + s)) * 2304 + h * 64;
    const float2* rp = (const float2*)rope;
#pragma unroll
    for (int mch = 0; mch < 4; ++mch){
      const int d0 = dbase + mch * 8;
      uint4 qv = *(const uint4*)&qkv[tokb + d0];
      uint4 kv = *(const uint4*)&qkv[tokb + 768 + d0];
      uint4 vv = *(const uint4*)&qkv[tokb + 1536 + d0];
      unsigned qin[4] = {qv.x, qv.y, qv.z, qv.w};
      unsigned kin[4] = {kv.x, kv.y, kv.z, kv.w};
      unsigned qo[4], ko[4];
#pragma unroll
      for (int j = 0; j < 4; ++j){
        float2 cssn = rp[r * 32 + (d0 >> 1) + j];
        float cs = cssn.x, sn = cssn.y;
        float qe = blo(qin[j]), qd = bhi(qin[j]);
        float ke = blo(kin[j]), kd = bhi(kin[j]);
        qo[j] = (unsigned)f2b(qe * cs - qd * sn) | ((unsigned)f2b(qe * sn + qd * cs) << 16);
        ko[j] = (unsigned)f2b(ke * cs - kd * sn) | ((unsigned)f2b(ke * sn + kd * cs) << 16);
      }
      const int byq = r * 128 + ((d0 * 2) ^ ((r & 7) << 4));
      *(uint4*)((char*)Qs + byq) = make_uint4(qo[0], qo[1], qo[2], qo[3]);
      *(uint4*)((char*)Ks + byq) = make_uint4(ko[0], ko[1], ko[2], ko[3]);
      unsigned vin[4] = {vv.x, vv.y, vv.z, vv.w};
#pragma unroll
      for (int j = 0; j < 8; ++j){
        const int d = d0 + j;
        unsigned short val = (j & 1) ? (unsigned short)(vin[j >> 1] >> 16)
                                     : (unsigned short)(vin[j >> 1] & 0xffffu);
        *(unsigned short*)((char*)Vt + d * 256 + ((r * 2) ^ ((d & 7) << 4))) = val;
      }
    }
  }
  __syncthreads();

  const int qbase = w * 32;
  f32x4 st[8][2];
#pragma unroll
  for (int i = 0; i < 8; ++i){ st[i][0] = f32x4{0.f,0.f,0.f,0.f}; st[i][1] = f32x4{0.f,0.f,0.f,0.f}; }
#pragma unroll
  for (int kd = 0; kd < 2; ++kd){
    short8 bq[2];
#pragma unroll
    for (int fq = 0; fq < 2; ++fq){
      const int qr = qbase + fq * 16 + llo;
      bq[fq] = *(const short8*)((const char*)Qs + qr * 128 + ((kd * 64 + lhi * 16) ^ ((qr & 7) << 4)));
    }
#pragma unroll
    for (int fk = 0; fk < 8; ++fk){
      const int kr = fk * 16 + llo;
      short8 ak = *(const short8*)((const char*)Ks + kr * 128 + ((kd * 64 + lhi * 16) ^ ((kr & 7) << 4)));
      st[fk][0] = __builtin_amdgcn_mfma_f32_16x16x32_bf16(ak, bq[0], st[fk][0], 0, 0, 0);
      st[fk][1] = __builtin_amdgcn_mfma_f32_16x16x32_bf16(ak, bq[1], st[fk][1], 0, 0, 0);
    }
  }

#pragma unroll
  for (int fq = 0; fq < 2; ++fq){
    const int qg = qbase + fq * 16 + llo;
    float m = -1e30f;
#pragma unroll
    for (int fk = 0; fk < 8; ++fk)
#pragma unroll
      for (int rr = 0; rr < 4; ++rr){
        const int kg = fk * 16 + lhi * 4 + rr;
        float sv = (kg <= qg) ? st[fk][fq][rr] : -1e30f;
        st[fk][fq][rr] = sv;
        m = fmaxf(m, sv);
      }
    m = fmaxf(m, __shfl_xor(m, 16, 64));
    m = fmaxf(m, __shfl_xor(m, 32, 64));
    float su = 0.f;
#pragma unroll
    for (int fk = 0; fk < 8; ++fk)
#pragma unroll
      for (int rr = 0; rr < 4; ++rr){
        float p = __expf((st[fk][fq][rr] - m) * 0.125f);
        st[fk][fq][rr] = p;
        su += p;
      }
    su += __shfl_xor(su, 16, 64);
    su += __shfl_xor(su, 32, 64);
    const float rs = 1.0f / su;
#pragma unroll
    for (int fk = 0; fk < 8; ++fk){
      const int kk = fk * 16 + lhi * 4;
      unsigned lo = (unsigned)f2b(st[fk][fq][0] * rs) | ((unsigned)f2b(st[fk][fq][1] * rs) << 16);
      unsigned hi = (unsigned)f2b(st[fk][fq][2] * rs) | ((unsigned)f2b(st[fk][fq][3] * rs) << 16);
      *(uint2*)((char*)P + qg * 256 + ((kk * 2) ^ ((qg & 7) << 4))) = make_uint2(lo, hi);
    }
  }
  __syncthreads();

  f32x4 oacc[2][4];
#pragma unroll
  for (int i = 0; i < 2; ++i)
#pragma unroll
    for (int j = 0; j < 4; ++j) oacc[i][j] = f32x4{0.f,0.f,0.f,0.f};
#pragma unroll
  for (int ks = 0; ks < 4; ++ks){
    short8 pa[2];
#pragma unroll
    for (int fq = 0; fq < 2; ++fq){
      const int qr = qbase + fq * 16 + llo;
      pa[fq] = *(const short8*)((const char*)P + qr * 256 + ((ks * 64 + lhi * 16) ^ ((qr & 7) << 4)));
    }
#pragma unroll
    for (int fd = 0; fd < 4; ++fd){
      const int dr = fd * 16 + llo;
      short8 vb = *(const short8*)((const char*)Vt + dr * 256 + ((ks * 64 + lhi * 16) ^ ((dr & 7) << 4)));
      oacc[0][fd] = __builtin_amdgcn_mfma_f32_16x16x32_bf16(pa[0], vb, oacc[0][fd], 0, 0, 0);
      oacc[1][fd] = __builtin_amdgcn_mfma_f32_16x16x32_bf16(pa[1], vb, oacc[1][fd], 0, 0, 0);
    }
  }

#pragma unroll
  for (int fq = 0; fq < 2; ++fq)
#pragma unroll
    for (int fd = 0; fd < 4; ++fd)
#pragma unroll
      for (int rr = 0; rr < 4; ++rr){
        const int qg = qbase + fq * 16 + lhi * 4 + rr;
        const int d = fd * 16 + llo;
        const size_t ob = ((size_t)((b * 128 + qg) * 16 + s)) * 768 + h * 64 + d;
        o[ob] = f2b(oacc[fq][fd][rr]);
      }
}

__global__ __launch_bounds__(256) void sentinel_k(float* out){
  if (blockIdx.x == 0 && threadIdx.x == 0) out[0] = 12345.0f;
}

// ---------------- launch ----------------
extern "C" void kernel_launch(void* const* d_in, const int* in_sizes, int n_in,
                              void* d_out, int out_size, void* d_ws, size_t ws_size,
                              hipStream_t stream){
  const float* x       = (const float*)d_in[0];
  const float* sn_g    = (const float*)d_in[2];
  const float* sn_b    = (const float*)d_in[3];
  const float* sa_in_w = (const float*)d_in[4];
  const float* sa_in_b = (const float*)d_in[5];
  const float* sa_out_w= (const float*)d_in[6];
  const float* sa_out_b= (const float*)d_in[7];
  const float* tn_g    = (const float*)d_in[8];
  const float* tn_b    = (const float*)d_in[9];
  const float* tq_w    = (const float*)d_in[10];
  const float* tq_b    = (const float*)d_in[11];
  const float* tk_w    = (const float*)d_in[12];
  const float* tk_b    = (const float*)d_in[13];
  const float* tv_w    = (const float*)d_in[14];
  const float* tv_b    = (const float*)d_in[15];
  const float* to_w    = (const float*)d_in[16];
  const float* to_b    = (const float*)d_in[17];
  const float* fn_g    = (const float*)d_in[18];
  const float* fn_b    = (const float*)d_in[19];
  const float* f1_w    = (const float*)d_in[20];
  const float* f1_b    = (const float*)d_in[21];
  const float* f2_w    = (const float*)d_in[22];
  const float* f2_b    = (const float*)d_in[23];

  char* ws = (char*)d_ws;
  size_t off = 0;
  auto alloc = [&](size_t bytes) -> void* {
    void* p = ws + off;
    off += (bytes + 255) & ~(size_t)255;
    return p;
  };
  unsigned short* Wqkv = (unsigned short*)alloc((size_t)2304*768*2);
  unsigned short* Wo1  = (unsigned short*)alloc((size_t)768*768*2);
  unsigned short* W3   = (unsigned short*)alloc((size_t)2304*768*2);
  float*          b3   = (float*)alloc(2304*4);
  unsigned short* Wto  = (unsigned short*)alloc((size_t)768*768*2);
  unsigned short* Wf1  = (unsigned short*)alloc((size_t)3072*768*2);
  unsigned short* Wf2  = (unsigned short*)alloc((size_t)768*3072*2);
  float*          rope = (float*)alloc(128*32*2*4);
  unsigned short* xn   = (unsigned short*)alloc((size_t)NTOK*768*2);
  unsigned short* qkv  = (unsigned short*)alloc((size_t)NTOK*3072*2);
  unsigned short* xs2  = (unsigned short*)alloc((size_t)NTOK*768*2);
  unsigned short* xt2  = (unsigned short*)alloc((size_t)NTOK*768*2);
  unsigned short* ob   = xn; // alias: xn dead when attn output written

  if (ws_size < off){ sentinel_k<<<1, 64, 0, stream>>>((float*)d_out); return; }

  convertall_k<<<2048, 256, 0, stream>>>(sa_in_w, sa_out_w, tq_w, tk_w, tv_w, to_w, f1_w, f2_w,
                                         Wqkv, Wo1, W3, W3 + 768*768, W3 + 2*768*768, Wto, Wf1, Wf2);
  concat3_k<<<3, 256, 0, stream>>>(tq_b, tk_b, tv_b, b3);
  rope_k<<<16, 256, 0, stream>>>(rope);

  // spatial block
  ln_k<1><<<NTOK, 256, 0, stream>>>(x, sn_g, sn_b, xn);
  gemm256_k<0><<<dim3(9, 128), 512, 0, stream>>>(xn, Wqkv, sa_in_b, nullptr, qkv, 768, 2304);
  sattn_k<<<dim3(2048, 12), 256, 0, stream>>>(qkv, ob);
  gemm256_k<2><<<dim3(3, 128), 512, 0, stream>>>(ob, Wo1, sa_out_b, x, xs2, 768, 768);

  // temporal block
  ln_k<0><<<NTOK, 256, 0, stream>>>(xs2, tn_g, tn_b, xn);
  gemm256_k<0><<<dim3(9, 128), 512, 0, stream>>>(xn, W3, b3, nullptr, qkv, 768, 2304);
  tattn_k<<<dim3(256, 12), 256, 0, stream>>>(qkv, rope, ob);
  gemm256_k<3><<<dim3(3, 128), 512, 0, stream>>>(ob, Wto, to_b, xs2, xt2, 768, 768);

  // FFN
  ln_k<0><<<NTOK, 256, 0, stream>>>(xt2, fn_g, fn_b, xn);
  gemm256_k<1><<<dim3(12, 128), 512, 0, stream>>>(xn, Wf1, f1_b, nullptr, qkv, 768, 3072);
  gemm256_k<4><<<dim3(3, 128), 512, 0, stream>>>(qkv, Wf2, f2_b, xt2, d_out, 3072, 768);
}